// Round 3
// baseline (277.060 us; speedup 1.0000x reference)
//
#include <hip/hip_runtime.h>
#include <hip/hip_bf16.h>

typedef __bf16 bf16;
typedef __attribute__((ext_vector_type(8))) __bf16 bf16x8;
typedef __attribute__((ext_vector_type(4))) __bf16 bf16x4;
typedef __attribute__((ext_vector_type(2))) __bf16 bf16x2;
typedef __attribute__((ext_vector_type(4))) float f32x4;
typedef __attribute__((ext_vector_type(2))) unsigned int u32x2;
typedef __attribute__((ext_vector_type(4))) unsigned int u32x4;

#define MFMA16(a, b, c) __builtin_amdgcn_mfma_f32_16x16x32_bf16((a), (b), (c), 0, 0, 0)
#define SM_SCALE 0.18033688011112043f  // (1/8) * log2(e), folded into q at GEMM epilogue

__device__ __forceinline__ void gld_lds16(const bf16* g, bf16* l) {
    __builtin_amdgcn_global_load_lds((const __attribute__((address_space(1))) void*)g,
                                     (__attribute__((address_space(3))) void*)l, 16, 0, 0);
}

// raw barriers: no compiler-inserted vmcnt(0)/lgkmcnt(0) drain at each barrier.
#define PBAR() asm volatile("s_barrier" ::: "memory")
#define VWAIT0() asm volatile("s_waitcnt vmcnt(0)" ::: "memory")
#define LWAIT0() asm volatile("s_waitcnt lgkmcnt(0)" ::: "memory")

// ---------------- W [K][N] f32 -> Wt [N][K] bf16, 3 weights in one launch ----------------
__global__ __launch_bounds__(256) void transpose_w3(const float* __restrict__ W0,
                                                    const float* __restrict__ W1,
                                                    const float* __restrict__ W2,
                                                    bf16* __restrict__ Wt) {
    const float* W = (blockIdx.z == 0) ? W0 : ((blockIdx.z == 1) ? W1 : W2);
    bf16* dst = Wt + (size_t)blockIdx.z * 1024 * 1024;
    __shared__ float tile[64][65];
    const int r0 = blockIdx.y * 64;  // k
    const int c0 = blockIdx.x * 64;  // n
    const int tid = threadIdx.x;
    for (int i = tid; i < 4096; i += 256) {
        int r = i >> 6, cc = i & 63;
        tile[r][cc] = W[(size_t)(r0 + r) * 1024 + c0 + cc];
    }
    __syncthreads();
    for (int i = tid; i < 4096; i += 256) {
        int n = i >> 6, k = i & 63;
        dst[(size_t)(c0 + n) * 1024 + r0 + k] = (bf16)tile[k][n];
    }
}

// ---------------- QKV GEMM: 256x256 tile, BK=64, 8 waves, 4-phase/K-tile ----------------
// A read directly from x (f32): reg-staged (global f32 -> cvt_pk bf16 -> ds_write at the
// ph2/ph3 seam, lgkm drains under ph3's MFMA). B via global_load_lds. Eliminates the
// standalone cvt_x pass (201 MB HBM). Numerics identical (same RNE f32->bf16 cast).
#define QKV_PHASE(MH, COFF, READB)                                                        \
    {                                                                                     \
        if (READB) {                                                                      \
            _Pragma("unroll") for (int ni = 0; ni < 4; ni++) bfrag[ni] =                  \
                *(const bf16x8*)&Bsp[((wc * 64 + ni * 16 + l16) << 6) + (COFF)];          \
        }                                                                                 \
        bf16x8 af[4];                                                                     \
        _Pragma("unroll") for (int m4 = 0; m4 < 4; m4++) af[m4] =                         \
            *(const bf16x8*)&Asp[((wr * 128 + (MH)*64 + m4 * 16 + l16) << 6) + (COFF)];   \
        __builtin_amdgcn_s_setprio(1);                                                    \
        _Pragma("unroll") for (int m4 = 0; m4 < 4; m4++)                                  \
            _Pragma("unroll") for (int ni = 0; ni < 4; ni++) acc[(MH)*4 + m4][ni] =       \
                MFMA16(af[m4], bfrag[ni], acc[(MH)*4 + m4][ni]);                          \
        __builtin_amdgcn_s_setprio(0);                                                    \
    }

__global__ __launch_bounds__(512, 2) void gemm_qkv(const float* __restrict__ Af,
                                                   const bf16* __restrict__ Bt,
                                                   const float* __restrict__ b0,
                                                   const float* __restrict__ b1,
                                                   const float* __restrict__ b2,
                                                   bf16* __restrict__ qb,
                                                   bf16* __restrict__ kb,
                                                   bf16* __restrict__ Vt) {
    __shared__ alignas(16) bf16 LDS[65536];  // 128 KiB: 2 bufs x (A 256x64 | B 256x64)

    // XCD-chunked bijective swizzle: 384 blocks, 48/XCD.
    const int orig = blockIdx.x;
    const int swz = (orig & 7) * 48 + (orig >> 3);
    const int by = swz / 12, bx = swz % 12;
    const int m0 = by * 256, n0 = bx * 256;

    const int tid = threadIdx.x;
    const int wid = tid >> 6, lane = tid & 63;
    const int wr = wid >> 2, wc = wid & 3;  // wave grid 2M x 4N; per-wave out 128x64
    const int quad = lane >> 4, l16 = lane & 15;

    // staging: thread covers rows sr+{0,64,128,192}; 16B chunk, source pre-swizzled
    const int sr = tid >> 3;
    const int scol = (((tid & 7) ^ (sr & 7)) * 8);
    const float* gA = Af + (size_t)(m0 + sr) * 1024 + scol;
    const bf16* gB = Bt + (size_t)(n0 + sr) * 1024 + scol;
    bf16* lbase = &LDS[tid * 8];

    // read-side swizzled column offsets
    const int xorE = (l16 & 7) * 8;
    const int coff0 = (quad * 8) ^ xorE;
    const int coff1 = (32 + quad * 8) ^ xorE;

    f32x4 acc[8][4] = {};
    bf16x8 bfrag[4];
    float4 av[8];

    auto LOADA = [&](int kt) {
        const float* a = gA + kt * 64;
#pragma unroll
        for (int i = 0; i < 4; i++) {
            av[2 * i] = *(const float4*)(a + (size_t)i * 64 * 1024);
            av[2 * i + 1] = *(const float4*)(a + (size_t)i * 64 * 1024 + 4);
        }
    };
    auto WRITEA = [&](int p) {
        bf16* la = lbase + p * 32768;
#pragma unroll
        for (int i = 0; i < 4; i++) {
            bf16x8 w = {(bf16)av[2 * i].x,     (bf16)av[2 * i].y,
                        (bf16)av[2 * i].z,     (bf16)av[2 * i].w,
                        (bf16)av[2 * i + 1].x, (bf16)av[2 * i + 1].y,
                        (bf16)av[2 * i + 1].z, (bf16)av[2 * i + 1].w};
            *(bf16x8*)&la[i * 4096] = w;
        }
    };
    auto STAGEB = [&](int kt, int p) {
        const bf16* b = gB + kt * 64;
        bf16* lb = lbase + p * 32768 + 16384;
        gld_lds16(b, lb);
        gld_lds16(b + 64 * 1024, lb + 4096);
        gld_lds16(b + 128 * 1024, lb + 8192);
        gld_lds16(b + 192 * 1024, lb + 12288);
    };

    LOADA(0);
    STAGEB(0, 0);
    VWAIT0();
    WRITEA(0);
    LWAIT0();
    PBAR();

#pragma unroll 1
    for (int kt = 0; kt < 16; kt++) {
        const int p = kt & 1;
        const bf16* Asp = &LDS[p * 32768];
        const bf16* Bsp = Asp + 16384;
        if (kt + 1 < 16) {
            LOADA(kt + 1);
            STAGEB(kt + 1, p ^ 1);
        }
        QKV_PHASE(0, coff0, true);
        PBAR();
        QKV_PHASE(1, coff0, false);
        PBAR();
        QKV_PHASE(0, coff1, true);
        if (kt + 1 < 16) {
            VWAIT0();       // drains B's gld_lds (issued ~2.5 phases ago) + A reg loads
            WRITEA(p ^ 1);  // A cvt+write; lgkm drains under ph3's MFMA
        }
        PBAR();
        QKV_PHASE(1, coff1, false);
        if (kt + 1 < 16) {
            LWAIT0();  // A ds_writes visible before publishing barrier
            PBAR();    // closing barrier: publishes kt+1, releases buf[p]
        }
    }

    // epilogue
    const int sel = n0 >> 10;  // 0=q, 1=k, 2=v  (256 | 1024 -> never straddles)
    const int nl0 = (n0 & 1023) + wc * 64;
    const int mb0 = m0 + wr * 128;
    if (sel < 2) {
        const float* bias = (sel == 0) ? b0 : b1;
        bf16* Cp = (sel == 0) ? qb : kb;
        const float qs = (sel == 0) ? SM_SCALE : 1.0f;
#pragma unroll
        for (int mi = 0; mi < 8; mi++) {
            const int mbase = mb0 + mi * 16 + quad * 4;
#pragma unroll
            for (int ni = 0; ni < 4; ni++) {
                const int nl = nl0 + ni * 16 + l16;
                const float bv = bias[nl];
#pragma unroll
                for (int r = 0; r < 4; r++)
                    Cp[(size_t)(mbase + r) * 1024 + nl] = (bf16)((acc[mi][ni][r] + bv) * qs);
            }
        }
    } else {
        const int b = m0 >> 11;  // 2048 rows/batch; 256-row block never straddles
#pragma unroll
        for (int ni = 0; ni < 4; ni++) {
            const int nl = nl0 + ni * 16 + l16;
            const int h = nl >> 6, d = nl & 63;
            const float bv = b2[nl];
            bf16* dst = Vt + ((size_t)(b * 16 + h) * 64 + d) * 2048;
#pragma unroll
            for (int mi = 0; mi < 8; mi++) {
                const int t0 = (mb0 + mi * 16 + quad * 4) & 2047;  // batch-local t
                bf16x4 w = {(bf16)(acc[mi][ni][0] + bv), (bf16)(acc[mi][ni][1] + bv),
                            (bf16)(acc[mi][ni][2] + bv), (bf16)(acc[mi][ni][3] + bv)};
                *(bf16x4*)&dst[t0] = w;
            }
        }
    }
}

// ---------------- GEMM: C = A[M,K] @ Bt[N,K]^T + bias (output projection) ----------------
template <int MODE>
__global__ __launch_bounds__(256) void gemm_bt(const bf16* __restrict__ A,
                                               const bf16* __restrict__ Bt,
                                               const float* __restrict__ b0,
                                               void* __restrict__ out0,
                                               int M, int N, int K) {
    __shared__ alignas(16) bf16 As[128 * 32];
    __shared__ alignas(16) bf16 Bs[128 * 32];
    const int tid = threadIdx.x;
    const int wave = tid >> 6, lane = tid & 63;
    const int quad = lane >> 4, l16 = lane & 15;
    const int m0 = blockIdx.y * 128, n0 = blockIdx.x * 128;
    const int wm = (wave & 1) * 64, wn = (wave >> 1) * 64;

    f32x4 acc[4][4] = {};

    const int srow = lane >> 2, scol = (lane & 3) * 8;
    const bf16* ga = A + (size_t)(m0 + wave * 32 + srow) * K + scol;
    const bf16* gb = Bt + (size_t)(n0 + wave * 32 + srow) * K + scol;
    bf16* la = &As[(wave * 32) * 32];
    bf16* lb = &Bs[(wave * 32) * 32];

    for (int k0 = 0; k0 < K; k0 += 32) {
        __syncthreads();
        gld_lds16(ga + k0, la);
        gld_lds16(ga + k0 + (size_t)16 * K, la + 16 * 32);
        gld_lds16(gb + k0, lb);
        gld_lds16(gb + k0 + (size_t)16 * K, lb + 16 * 32);
        __syncthreads();
        bf16x8 af[4], bfr[4];
#pragma unroll
        for (int mi = 0; mi < 4; mi++)
            af[mi] = *(const bf16x8*)&As[(wm + mi * 16 + l16) * 32 + quad * 8];
#pragma unroll
        for (int ni = 0; ni < 4; ni++)
            bfr[ni] = *(const bf16x8*)&Bs[(wn + ni * 16 + l16) * 32 + quad * 8];
#pragma unroll
        for (int mi = 0; mi < 4; mi++)
#pragma unroll
            for (int ni = 0; ni < 4; ni++)
                acc[mi][ni] = MFMA16(af[mi], bfr[ni], acc[mi][ni]);
    }

    float* Cp = (float*)out0;
#pragma unroll
    for (int mi = 0; mi < 4; mi++) {
        const int mbase = m0 + wm + mi * 16 + quad * 4;
#pragma unroll
        for (int ni = 0; ni < 4; ni++) {
            const int n = n0 + wn + ni * 16 + l16;
            const float bv = b0[n];
#pragma unroll
            for (int r = 0; r < 4; r++)
                Cp[(size_t)(mbase + r) * 1024 + n] = acc[mi][ni][r] + bv;
        }
    }
}

// ---------------- flash attention, causal, hs=64 ----------------
// R9 changes vs R8 (VALU/overhead cuts; structure and math layout unchanged):
//  * K/V staging via global_load_lds (pre-swizzled source, rule #21) into a linear
//    stride-64 LDS tile, reads XOR-swizzled: kills the reg round-trip (4 ds_write +
//    8 movs/tile) and residual bank conflicts. LDS 36864 -> 32768.
//  * l-sum via MFMA ones-fragment: lacc = mfma(ones, pf, lacc) replaces 16
//    v_add_f32/tile + the end shuffles. Sums the same bf16 P that PV consumes.
//  * Raw s_barrier per tile with a single vmcnt(0) at compute end (gld_lds prefetch
//    flies across the whole tile's compute).
template <bool NEEDMASK>
__device__ __forceinline__ void softmax_reg(const f32x4* st, bf16x8* pf, int qrel) {
    unsigned int p[4][2];
#pragma unroll
    for (int j = 0; j < 4; j++) {
        float pv[4];
#pragma unroll
        for (int r = 0; r < 4; r++) {
            float s = st[j][r];
            if (NEEDMASK && (j * 16 + r > qrel)) s = -1e30f;
            pv[r] = exp2f(s);
        }
        bf16x2 w0 = {(bf16)pv[0], (bf16)pv[1]};  // v_cvt_pk_bf16_f32 (compiler-fused)
        bf16x2 w1 = {(bf16)pv[2], (bf16)pv[3]};
        p[j][0] = __builtin_bit_cast(unsigned int, w0);
        p[j][1] = __builtin_bit_cast(unsigned int, w1);
    }
    // acc layout -> B-frag layout: permlane32_swap then permlane16_swap (l16 invariant)
#pragma unroll
    for (int ks = 0; ks < 2; ks++) {
        unsigned int q4[4];
#pragma unroll
        for (int h = 0; h < 2; h++) {
            u32x2 s32 = __builtin_amdgcn_permlane32_swap(p[2 * ks][h], p[2 * ks + 1][h],
                                                         false, false);
            u32x2 s16 = __builtin_amdgcn_permlane16_swap(s32[0], s32[1], false, false);
            q4[h] = s16[0];      // e2 = h     (kv ofs 2h, 2h+1)
            q4[2 + h] = s16[1];  // e2 = 2+h   (kv ofs 4+2h, 5+2h)
        }
        u32x4 qq = {q4[0], q4[1], q4[2], q4[3]};
        pf[ks] = __builtin_bit_cast(bf16x8, qq);
    }
}

__global__ __launch_bounds__(256, 4) void attn(const bf16* __restrict__ Q,
                                               const bf16* __restrict__ Kg,
                                               const bf16* __restrict__ Vt,
                                               bf16* __restrict__ O) {
    // bijective XCD swizzle: all 16 j-blocks of a (b,h) on one XCD (8 bh/XCD).
    const int lin = blockIdx.y * 16 + blockIdx.x;
    const int bh = (lin & 7) * 8 + ((lin >> 3) & 7);
    const int jb = lin >> 6;  // [0,16)
    const int b = bh >> 4, h = bh & 15;
    const int tid = threadIdx.x;
    const int wave = tid >> 6, lane = tid & 63;
    const int quad = lane >> 4, l16 = lane & 15;

    __shared__ alignas(16) bf16 KVs[2 * 8192];  // dbuf; per buf: K 64x64 | V^T 64x64 (swz)

    const bf16* Kbase = Kg + ((size_t)b * 2048) * 1024 + h * 64;
    const bf16* Vbase = Vt + (size_t)bh * 64 * 2048;

    // staging geometry: thread covers rows (tid>>3) and (tid>>3)+32 (same &7), 16B
    // chunk pre-swizzled so linear LDS + XOR read yields logical data (rule #21).
    const int srow = tid >> 3;
    const int schunk = (tid & 7) ^ (srow & 7);

    // read-side swizzled column offsets (elements); K/V row&7 == l16&7 for all j/db
    const int xorE = (l16 & 7) * 8;
    const int cofA = (quad * 8) ^ xorE;         // ks=0
    const int cofB = (32 + quad * 8) ^ xorE;    // ks=1

    const bf16 one1 = (bf16)1.0f;
    const bf16x8 onesf = {one1, one1, one1, one1, one1, one1, one1, one1};

#pragma unroll 1
    for (int phase = 0; phase < 2; phase++) {
        // causal pairing at 64-q granularity: strip (31-j) then j -> 33 tiles total
        const int qs = (phase == 0) ? (31 - jb) : jb;
        const int q0 = qs * 64;
        const bf16* Qbase = Q + ((size_t)(b * 2048 + q0)) * 1024 + h * 64;

        bf16x8 qf[2];
#pragma unroll
        for (int ks = 0; ks < 2; ks++)
            qf[ks] = *(const bf16x8*)&Qbase[(size_t)(wave * 16 + l16) * 1024 + ks * 32 + quad * 8];

        f32x4 ot[4] = {};
        f32x4 lacc = {0.f, 0.f, 0.f, 0.f};
        const int ntiles = qs + 1;
        const int qrel = wave * 16 + l16 - quad * 4;

        // rolling per-lane global staging pointers
        const bf16* pK = Kbase + (size_t)srow * 1024 + schunk * 8;
        const bf16* pK2 = pK + (size_t)32 * 1024;
        const bf16* pV = Vbase + (size_t)srow * 2048 + schunk * 8;
        const bf16* pV2 = pV + (size_t)32 * 2048;

        // prologue: stage tile 0 into buf0
        {
            bf16* nb = &KVs[tid * 8];
            gld_lds16(pK, nb);
            gld_lds16(pK2, nb + 2048);
            gld_lds16(pV, nb + 4096);
            gld_lds16(pV2, nb + 6144);
            pK += 64 * 1024; pK2 += 64 * 1024; pV += 64; pV2 += 64;
        }
        VWAIT0();
        PBAR();

#pragma unroll 1
        for (int tk = 0; tk < ntiles; tk++) {
            const bf16* buf = &KVs[(tk & 1) * 8192];
            if (tk + 1 < ntiles) {  // prefetch next tile straight to the other buffer
                bf16* nb = &KVs[((tk + 1) & 1) * 8192 + tid * 8];
                gld_lds16(pK, nb);
                gld_lds16(pK2, nb + 2048);
                gld_lds16(pV, nb + 4096);
                gld_lds16(pV2, nb + 6144);
                pK += 64 * 1024; pK2 += 64 * 1024; pV += 64; pV2 += 64;
            }

            // S^T = K . Q^T
            f32x4 st[4] = {};
#pragma unroll
            for (int ks = 0; ks < 2; ks++)
#pragma unroll
                for (int j = 0; j < 4; j++) {
                    const bf16x8 kf =
                        *(const bf16x8*)&buf[(j * 16 + l16) * 64 + (ks ? cofB : cofA)];
                    st[j] = MFMA16(kf, qf[ks], st[j]);
                }

            // softmax + in-register P redistribution
            bf16x8 pf[2];
            if (tk == ntiles - 1)
                softmax_reg<true>(st, pf, qrel);
            else
                softmax_reg<false>(st, pf, qrel);

            // l-sum via MFMA (all 16 rows of D = full column sum; lane reads lacc[0])
            lacc = MFMA16(onesf, pf[0], lacc);
            lacc = MFMA16(onesf, pf[1], lacc);

            // O^T += V^T . P^T
#pragma unroll
            for (int ks = 0; ks < 2; ks++)
#pragma unroll
                for (int db = 0; db < 4; db++) {
                    const bf16x8 vf = *(const bf16x8*)&buf[4096 + (db * 16 + l16) * 64 +
                                                           (ks ? cofB : cofA)];
                    ot[db] = MFMA16(vf, pf[ks], ot[db]);
                }

            if (tk + 1 < ntiles) VWAIT0();  // gld_lds issued a full compute-tile ago
            PBAR();  // publishes tk+1; all reads of buf[tk&1] done -> free for tk+2
        }

        // epilogue: O^T regs -> transpose staging in the idle dbuf half, viewed as
        // stride-72 rows (bank-balanced). buf[ntiles&1]'s readers finished before the
        // last tile's barrier; per-wave disjoint 16x72 slices (4*1152 <= 8192).
        const float inv = 1.f / lacc[0];
        bf16* ep = &KVs[(ntiles & 1) * 8192 + wave * (16 * 72)];
#pragma unroll
        for (int db = 0; db < 4; db++) {
            bf16x4 w = {(bf16)(ot[db][0] * inv), (bf16)(ot[db][1] * inv),
                        (bf16)(ot[db][2] * inv), (bf16)(ot[db][3] * inv)};
            *(bf16x4*)&ep[l16 * 72 + db * 16 + quad * 4] = w;
        }
        {
            const int orow = lane >> 2, oc = (lane & 3) * 16;  // 16 rows x 64 cols/wave
            bf16* Obase =
                O + ((size_t)(b * 2048 + q0 + wave * 16 + orow)) * 1024 + h * 64 + oc;
            const bf16* src = &ep[orow * 72 + oc];
            *(bf16x8*)&Obase[0] = *(const bf16x8*)&src[0];
            *(bf16x8*)&Obase[8] = *(const bf16x8*)&src[8];
        }
        __syncthreads();  // epilogue reads done before next phase's prologue staging
    }
}

extern "C" void kernel_launch(void* const* d_in, const int* in_sizes, int n_in,
                              void* d_out, int out_size, void* d_ws, size_t ws_size,
                              hipStream_t stream) {
    const float* x = (const float*)d_in[0];
    const float* Wq = (const float*)d_in[1];
    const float* bq = (const float*)d_in[2];
    const float* Wk = (const float*)d_in[3];
    const float* bk = (const float*)d_in[4];
    const float* Wv = (const float*)d_in[5];
    const float* bv = (const float*)d_in[6];
    float* out = (float*)d_out;

    const int M = 8192;  // B*T
    const size_t sz_x = (size_t)M * 1024;
    const size_t sz_w = (size_t)1024 * 1024;

    char* p = (char*)d_ws;
    bf16* Wcat = (bf16*)p; p += 3 * sz_w * 2;  // [Wq^T ; Wk^T ; Wv^T]
    bf16* qb = (bf16*)p;   p += sz_x * 2;
    bf16* kb = (bf16*)p;   p += sz_x * 2;
    bf16* Vt = (bf16*)p;   p += sz_x * 2;  // [B*H][64][2048]
    bf16* yatt = (bf16*)p; p += sz_x * 2;

    transpose_w3<<<dim3(16, 16, 3), dim3(256), 0, stream>>>(Wq, Wk, Wv, Wcat);

    // fused QKV projection: x(f32) [8192,1024] @ [1024,3072], cvt folded into staging
    gemm_qkv<<<dim3(384), dim3(512), 0, stream>>>(x, Wcat, bq, bk, bv, qb, kb, Vt);
    attn<<<dim3(16, 64), dim3(256), 0, stream>>>(qb, kb, Vt, yatt);
    // output projection (reference reuses v_proj): yatt @ Wv + bv -> f32 out
    gemm_bt<1><<<dim3(8, 64), dim3(256), 0, stream>>>(yatt, Wcat + 2 * sz_w, bv,
                                                      out, M, 1024, 1024);
}

// Round 4
// 256.099 us; speedup vs baseline: 1.0818x; 1.0818x over previous
//
#include <hip/hip_runtime.h>
#include <hip/hip_bf16.h>

typedef __bf16 bf16;
typedef __attribute__((ext_vector_type(8))) __bf16 bf16x8;
typedef __attribute__((ext_vector_type(4))) __bf16 bf16x4;
typedef __attribute__((ext_vector_type(2))) __bf16 bf16x2;
typedef __attribute__((ext_vector_type(4))) float f32x4;
typedef __attribute__((ext_vector_type(2))) unsigned int u32x2;
typedef __attribute__((ext_vector_type(4))) unsigned int u32x4;

#define MFMA16(a, b, c) __builtin_amdgcn_mfma_f32_16x16x32_bf16((a), (b), (c), 0, 0, 0)
#define SM_SCALE 0.18033688011112043f  // (1/8) * log2(e), folded into q at GEMM epilogue

__device__ __forceinline__ void gld_lds16(const bf16* g, bf16* l) {
    __builtin_amdgcn_global_load_lds((const __attribute__((address_space(1))) void*)g,
                                     (__attribute__((address_space(3))) void*)l, 16, 0, 0);
}

// raw barriers: no compiler-inserted vmcnt(0)/lgkmcnt(0) drain at each barrier.
#define PBAR() asm volatile("s_barrier" ::: "memory")
#define VWAIT0() asm volatile("s_waitcnt vmcnt(0)" ::: "memory")

// ---------------- f32 -> bf16 convert (x) ----------------
__global__ __launch_bounds__(256) void cvt_x(const float* __restrict__ in,
                                             bf16* __restrict__ outb, int n) {
    int i = (blockIdx.x * 256 + threadIdx.x) * 4;
    if (i + 3 < n) {
        const float4 v = *(const float4*)(in + i);
        bf16x4 o = {(bf16)v.x, (bf16)v.y, (bf16)v.z, (bf16)v.w};
        *(bf16x4*)(outb + i) = o;
    }
}

// ---------------- W [K][N] f32 -> Wt [N][K] bf16, 3 weights in one launch ----------------
__global__ __launch_bounds__(256) void transpose_w3(const float* __restrict__ W0,
                                                    const float* __restrict__ W1,
                                                    const float* __restrict__ W2,
                                                    bf16* __restrict__ Wt) {
    const float* W = (blockIdx.z == 0) ? W0 : ((blockIdx.z == 1) ? W1 : W2);
    bf16* dst = Wt + (size_t)blockIdx.z * 1024 * 1024;
    __shared__ float tile[64][65];
    const int r0 = blockIdx.y * 64;  // k
    const int c0 = blockIdx.x * 64;  // n
    const int tid = threadIdx.x;
    for (int i = tid; i < 4096; i += 256) {
        int r = i >> 6, cc = i & 63;
        tile[r][cc] = W[(size_t)(r0 + r) * 1024 + c0 + cc];
    }
    __syncthreads();
    for (int i = tid; i < 4096; i += 256) {
        int n = i >> 6, k = i & 63;
        dst[(size_t)(c0 + n) * 1024 + r0 + k] = (bf16)tile[k][n];
    }
}

// ---------------- QKV GEMM: 256x128 tile, BK=32, 8 waves (4Mx2N), 64x64/wave ----------------
// R10: occupancy-driven regeometry. acc=64 regs/wave -> total <=128 (launch_bounds(512,4))
// -> 4 waves/SIMD; LDS 48KiB -> 2 blocks/CU resident = 16 waves/CU (2x TLP vs 256^2).
// One raw barrier + one vmcnt(0) per K-tile; dbuf staging issued a full tile-body before
// its wait. Both-sides XOR swizzle (col ^= (row&3)*8): 32-col rows spread 4 banksets ->
// residual 4-way read conflict (1.58x) accepted, hidden under MFMA at 16 waves/CU.
__global__ __launch_bounds__(512, 4) void gemm_qkv(const bf16* __restrict__ A,
                                                   const bf16* __restrict__ Bt,
                                                   const float* __restrict__ b0,
                                                   const float* __restrict__ b1,
                                                   const float* __restrict__ b2,
                                                   bf16* __restrict__ qb,
                                                   bf16* __restrict__ kb,
                                                   bf16* __restrict__ Vt) {
    __shared__ alignas(16) bf16 LDS[2 * 12288];  // per buf: A 256x32 @0 | B 128x32 @8192

    // XCD-chunked bijective swizzle: 768 blocks, 96/XCD (4 M-rows x 24 N-cols per XCD
    // -> A-panels L2-hot across the N sweep; B/W panels L3-resident).
    const int orig = blockIdx.x;
    const int swz = (orig & 7) * 96 + (orig >> 3);
    const int by = swz / 24, bx = swz % 24;
    const int m0 = by * 256, n0 = bx * 128;

    const int tid = threadIdx.x;
    const int wid = tid >> 6, lane = tid & 63;
    const int wr = wid >> 1, wc = wid & 1;  // wave grid 4M x 2N; per-wave out 64x64
    const int quad = lane >> 4, l16 = lane & 15;

    // staging: thread t covers A rows (t>>2, 128+(t>>2)) and B row (t>>2), 16B chunk
    // (t&3); source col pre-swizzled so linear LDS + XOR read yields logical data.
    const int sr = tid >> 2;
    const int scol = (((tid & 3) ^ (sr & 3)) * 8);
    const bf16* gA = A + (size_t)(m0 + sr) * 1024 + scol;
    const bf16* gB = Bt + (size_t)(n0 + sr) * 1024 + scol;
    bf16* lA = &LDS[tid * 8];
    bf16* lB = &LDS[8192 + tid * 8];

    // read-side swizzled chunk (row&3 == l16&3 for all fragment rows)
    const int coff = ((quad ^ (l16 & 3)) * 8);

    f32x4 acc[4][4] = {};

    auto STAGE = [&](int kt, int p) {
        const int base = p * 12288;
        gld_lds16(gA + kt * 32, lA + base);
        gld_lds16(gA + kt * 32 + (size_t)128 * 1024, lA + base + 4096);
        gld_lds16(gB + kt * 32, lB + base);
    };

    STAGE(0, 0);
    VWAIT0();
    PBAR();

#pragma unroll 1
    for (int kt = 0; kt < 32; kt++) {
        const int p = kt & 1;
        const bf16* Asp = &LDS[p * 12288];
        const bf16* Bsp = Asp + 8192;
        if (kt + 1 < 32) STAGE(kt + 1, p ^ 1);  // buf[p^1] readers done at kt-1's barrier

        bf16x8 af[4], bfr[4];
#pragma unroll
        for (int m4 = 0; m4 < 4; m4++)
            af[m4] = *(const bf16x8*)&Asp[(wr * 64 + m4 * 16 + l16) * 32 + coff];
#pragma unroll
        for (int ni = 0; ni < 4; ni++)
            bfr[ni] = *(const bf16x8*)&Bsp[(wc * 64 + ni * 16 + l16) * 32 + coff];

        __builtin_amdgcn_s_setprio(1);
#pragma unroll
        for (int m4 = 0; m4 < 4; m4++)
#pragma unroll
            for (int ni = 0; ni < 4; ni++)
                acc[m4][ni] = MFMA16(af[m4], bfr[ni], acc[m4][ni]);
        __builtin_amdgcn_s_setprio(0);

        if (kt + 1 < 32) VWAIT0();  // stage(kt+1) issued a full tile-body (~1240cy) ago
        PBAR();                     // publishes kt+1; buf[p] reads done -> free for kt+2
    }

    // epilogue
    const int sel = n0 >> 10;  // 0=q, 1=k, 2=v  (128 | 1024 -> never straddles)
    const int nl0 = (n0 & 1023) + wc * 64;
    const int mb0 = m0 + wr * 64;
    if (sel < 2) {
        const float* bias = (sel == 0) ? b0 : b1;
        bf16* Cp = (sel == 0) ? qb : kb;
        const float qs = (sel == 0) ? SM_SCALE : 1.0f;
#pragma unroll
        for (int mi = 0; mi < 4; mi++) {
            const int mbase = mb0 + mi * 16 + quad * 4;
#pragma unroll
            for (int ni = 0; ni < 4; ni++) {
                const int nl = nl0 + ni * 16 + l16;
                const float bv = bias[nl];
#pragma unroll
                for (int r = 0; r < 4; r++)
                    Cp[(size_t)(mbase + r) * 1024 + nl] = (bf16)((acc[mi][ni][r] + bv) * qs);
            }
        }
    } else {
        const int b = m0 >> 11;  // 2048 rows/batch; 256-row block never straddles
#pragma unroll
        for (int ni = 0; ni < 4; ni++) {
            const int nl = nl0 + ni * 16 + l16;
            const int h = nl >> 6, d = nl & 63;
            const float bv = b2[nl];
            bf16* dst = Vt + ((size_t)(b * 16 + h) * 64 + d) * 2048;
#pragma unroll
            for (int mi = 0; mi < 4; mi++) {
                const int t0 = (mb0 + mi * 16 + quad * 4) & 2047;  // batch-local t
                bf16x4 w = {(bf16)(acc[mi][ni][0] + bv), (bf16)(acc[mi][ni][1] + bv),
                            (bf16)(acc[mi][ni][2] + bv), (bf16)(acc[mi][ni][3] + bv)};
                *(bf16x4*)&dst[t0] = w;
            }
        }
    }
}

// ---------------- GEMM: C = A[M,K] @ Bt[N,K]^T + bias (output projection) ----------------
template <int MODE>
__global__ __launch_bounds__(256) void gemm_bt(const bf16* __restrict__ A,
                                               const bf16* __restrict__ Bt,
                                               const float* __restrict__ b0,
                                               void* __restrict__ out0,
                                               int M, int N, int K) {
    __shared__ alignas(16) bf16 As[128 * 32];
    __shared__ alignas(16) bf16 Bs[128 * 32];
    const int tid = threadIdx.x;
    const int wave = tid >> 6, lane = tid & 63;
    const int quad = lane >> 4, l16 = lane & 15;
    const int m0 = blockIdx.y * 128, n0 = blockIdx.x * 128;
    const int wm = (wave & 1) * 64, wn = (wave >> 1) * 64;

    f32x4 acc[4][4] = {};

    const int srow = lane >> 2, scol = (lane & 3) * 8;
    const bf16* ga = A + (size_t)(m0 + wave * 32 + srow) * K + scol;
    const bf16* gb = Bt + (size_t)(n0 + wave * 32 + srow) * K + scol;
    bf16* la = &As[(wave * 32) * 32];
    bf16* lb = &Bs[(wave * 32) * 32];

    for (int k0 = 0; k0 < K; k0 += 32) {
        __syncthreads();
        gld_lds16(ga + k0, la);
        gld_lds16(ga + k0 + (size_t)16 * K, la + 16 * 32);
        gld_lds16(gb + k0, lb);
        gld_lds16(gb + k0 + (size_t)16 * K, lb + 16 * 32);
        __syncthreads();
        bf16x8 af[4], bfr[4];
#pragma unroll
        for (int mi = 0; mi < 4; mi++)
            af[mi] = *(const bf16x8*)&As[(wm + mi * 16 + l16) * 32 + quad * 8];
#pragma unroll
        for (int ni = 0; ni < 4; ni++)
            bfr[ni] = *(const bf16x8*)&Bs[(wn + ni * 16 + l16) * 32 + quad * 8];
#pragma unroll
        for (int mi = 0; mi < 4; mi++)
#pragma unroll
            for (int ni = 0; ni < 4; ni++)
                acc[mi][ni] = MFMA16(af[mi], bfr[ni], acc[mi][ni]);
    }

    float* Cp = (float*)out0;
#pragma unroll
    for (int mi = 0; mi < 4; mi++) {
        const int mbase = m0 + wm + mi * 16 + quad * 4;
#pragma unroll
        for (int ni = 0; ni < 4; ni++) {
            const int n = n0 + wn + ni * 16 + l16;
            const float bv = b0[n];
#pragma unroll
            for (int r = 0; r < 4; r++)
                Cp[(size_t)(mbase + r) * 1024 + n] = acc[mi][ni][r] + bv;
        }
    }
}

// ---------------- flash attention, causal, hs=64 (R9 structure, unchanged) ----------------
template <bool NEEDMASK>
__device__ __forceinline__ void softmax_reg(const f32x4* st, bf16x8* pf, int qrel) {
    unsigned int p[4][2];
#pragma unroll
    for (int j = 0; j < 4; j++) {
        float pv[4];
#pragma unroll
        for (int r = 0; r < 4; r++) {
            float s = st[j][r];
            if (NEEDMASK && (j * 16 + r > qrel)) s = -1e30f;
            pv[r] = exp2f(s);
        }
        bf16x2 w0 = {(bf16)pv[0], (bf16)pv[1]};  // v_cvt_pk_bf16_f32 (compiler-fused)
        bf16x2 w1 = {(bf16)pv[2], (bf16)pv[3]};
        p[j][0] = __builtin_bit_cast(unsigned int, w0);
        p[j][1] = __builtin_bit_cast(unsigned int, w1);
    }
    // acc layout -> B-frag layout: permlane32_swap then permlane16_swap (l16 invariant)
#pragma unroll
    for (int ks = 0; ks < 2; ks++) {
        unsigned int q4[4];
#pragma unroll
        for (int h = 0; h < 2; h++) {
            u32x2 s32 = __builtin_amdgcn_permlane32_swap(p[2 * ks][h], p[2 * ks + 1][h],
                                                         false, false);
            u32x2 s16 = __builtin_amdgcn_permlane16_swap(s32[0], s32[1], false, false);
            q4[h] = s16[0];      // e2 = h     (kv ofs 2h, 2h+1)
            q4[2 + h] = s16[1];  // e2 = 2+h   (kv ofs 4+2h, 5+2h)
        }
        u32x4 qq = {q4[0], q4[1], q4[2], q4[3]};
        pf[ks] = __builtin_bit_cast(bf16x8, qq);
    }
}

__global__ __launch_bounds__(256, 4) void attn(const bf16* __restrict__ Q,
                                               const bf16* __restrict__ Kg,
                                               const bf16* __restrict__ Vt,
                                               bf16* __restrict__ O) {
    // bijective XCD swizzle: all 16 j-blocks of a (b,h) on one XCD (8 bh/XCD).
    const int lin = blockIdx.y * 16 + blockIdx.x;
    const int bh = (lin & 7) * 8 + ((lin >> 3) & 7);
    const int jb = lin >> 6;  // [0,16)
    const int b = bh >> 4, h = bh & 15;
    const int tid = threadIdx.x;
    const int wave = tid >> 6, lane = tid & 63;
    const int quad = lane >> 4, l16 = lane & 15;

    __shared__ alignas(16) bf16 KVs[2 * 8192];  // dbuf; per buf: K 64x64 | V^T 64x64 (swz)

    const bf16* Kbase = Kg + ((size_t)b * 2048) * 1024 + h * 64;
    const bf16* Vbase = Vt + (size_t)bh * 64 * 2048;

    const int srow = tid >> 3;
    const int schunk = (tid & 7) ^ (srow & 7);

    const int xorE = (l16 & 7) * 8;
    const int cofA = (quad * 8) ^ xorE;       // ks=0
    const int cofB = (32 + quad * 8) ^ xorE;  // ks=1

    const bf16 one1 = (bf16)1.0f;
    const bf16x8 onesf = {one1, one1, one1, one1, one1, one1, one1, one1};

#pragma unroll 1
    for (int phase = 0; phase < 2; phase++) {
        const int qs = (phase == 0) ? (31 - jb) : jb;
        const int q0 = qs * 64;
        const bf16* Qbase = Q + ((size_t)(b * 2048 + q0)) * 1024 + h * 64;

        bf16x8 qf[2];
#pragma unroll
        for (int ks = 0; ks < 2; ks++)
            qf[ks] = *(const bf16x8*)&Qbase[(size_t)(wave * 16 + l16) * 1024 + ks * 32 + quad * 8];

        f32x4 ot[4] = {};
        f32x4 lacc = {0.f, 0.f, 0.f, 0.f};
        const int ntiles = qs + 1;
        const int qrel = wave * 16 + l16 - quad * 4;

        const bf16* pK = Kbase + (size_t)srow * 1024 + schunk * 8;
        const bf16* pK2 = pK + (size_t)32 * 1024;
        const bf16* pV = Vbase + (size_t)srow * 2048 + schunk * 8;
        const bf16* pV2 = pV + (size_t)32 * 2048;

        {
            bf16* nb = &KVs[tid * 8];
            gld_lds16(pK, nb);
            gld_lds16(pK2, nb + 2048);
            gld_lds16(pV, nb + 4096);
            gld_lds16(pV2, nb + 6144);
            pK += 64 * 1024; pK2 += 64 * 1024; pV += 64; pV2 += 64;
        }
        VWAIT0();
        PBAR();

#pragma unroll 1
        for (int tk = 0; tk < ntiles; tk++) {
            const bf16* buf = &KVs[(tk & 1) * 8192];
            if (tk + 1 < ntiles) {
                bf16* nb = &KVs[((tk + 1) & 1) * 8192 + tid * 8];
                gld_lds16(pK, nb);
                gld_lds16(pK2, nb + 2048);
                gld_lds16(pV, nb + 4096);
                gld_lds16(pV2, nb + 6144);
                pK += 64 * 1024; pK2 += 64 * 1024; pV += 64; pV2 += 64;
            }

            f32x4 st[4] = {};
#pragma unroll
            for (int ks = 0; ks < 2; ks++)
#pragma unroll
                for (int j = 0; j < 4; j++) {
                    const bf16x8 kf =
                        *(const bf16x8*)&buf[(j * 16 + l16) * 64 + (ks ? cofB : cofA)];
                    st[j] = MFMA16(kf, qf[ks], st[j]);
                }

            bf16x8 pf[2];
            if (tk == ntiles - 1)
                softmax_reg<true>(st, pf, qrel);
            else
                softmax_reg<false>(st, pf, qrel);

            lacc = MFMA16(onesf, pf[0], lacc);
            lacc = MFMA16(onesf, pf[1], lacc);

#pragma unroll
            for (int ks = 0; ks < 2; ks++)
#pragma unroll
                for (int db = 0; db < 4; db++) {
                    const bf16x8 vf = *(const bf16x8*)&buf[4096 + (db * 16 + l16) * 64 +
                                                           (ks ? cofB : cofA)];
                    ot[db] = MFMA16(vf, pf[ks], ot[db]);
                }

            if (tk + 1 < ntiles) VWAIT0();
            PBAR();
        }

        const float inv = 1.f / lacc[0];
        bf16* ep = &KVs[(ntiles & 1) * 8192 + wave * (16 * 72)];
#pragma unroll
        for (int db = 0; db < 4; db++) {
            bf16x4 w = {(bf16)(ot[db][0] * inv), (bf16)(ot[db][1] * inv),
                        (bf16)(ot[db][2] * inv), (bf16)(ot[db][3] * inv)};
            *(bf16x4*)&ep[l16 * 72 + db * 16 + quad * 4] = w;
        }
        {
            const int orow = lane >> 2, oc = (lane & 3) * 16;
            bf16* Obase =
                O + ((size_t)(b * 2048 + q0 + wave * 16 + orow)) * 1024 + h * 64 + oc;
            const bf16* src = &ep[orow * 72 + oc];
            *(bf16x8*)&Obase[0] = *(const bf16x8*)&src[0];
            *(bf16x8*)&Obase[8] = *(const bf16x8*)&src[8];
        }
        __syncthreads();
    }
}

extern "C" void kernel_launch(void* const* d_in, const int* in_sizes, int n_in,
                              void* d_out, int out_size, void* d_ws, size_t ws_size,
                              hipStream_t stream) {
    const float* x = (const float*)d_in[0];
    const float* Wq = (const float*)d_in[1];
    const float* bq = (const float*)d_in[2];
    const float* Wk = (const float*)d_in[3];
    const float* bk = (const float*)d_in[4];
    const float* Wv = (const float*)d_in[5];
    const float* bv = (const float*)d_in[6];
    float* out = (float*)d_out;

    const int M = 8192;  // B*T
    const size_t sz_x = (size_t)M * 1024;
    const size_t sz_w = (size_t)1024 * 1024;

    char* p = (char*)d_ws;
    bf16* xb = (bf16*)p;   p += sz_x * 2;
    bf16* Wcat = (bf16*)p; p += 3 * sz_w * 2;  // [Wq^T ; Wk^T ; Wv^T]
    bf16* qb = (bf16*)p;   p += sz_x * 2;
    bf16* kb = (bf16*)p;   p += sz_x * 2;
    bf16* Vt = (bf16*)p;   p += sz_x * 2;  // [B*H][64][2048]
    bf16* yatt = (bf16*)p; p += sz_x * 2;

    cvt_x<<<dim3(8192), dim3(256), 0, stream>>>(x, xb, (int)sz_x);
    transpose_w3<<<dim3(16, 16, 3), dim3(256), 0, stream>>>(Wq, Wk, Wv, Wcat);

    // fused QKV projection: [8192,1024] @ [1024,3072] -- 256x128/BK32, 16 waves/CU
    gemm_qkv<<<dim3(768), dim3(512), 0, stream>>>(xb, Wcat, bq, bk, bv, qb, kb, Vt);
    attn<<<dim3(16, 64), dim3(256), 0, stream>>>(qb, kb, Vt, yatt);
    // output projection (reference reuses v_proj): yatt @ Wv + bv -> f32 out
    gemm_bt<1><<<dim3(8, 64), dim3(256), 0, stream>>>(yatt, Wcat + 2 * sz_w, bv,
                                                      out, M, 1024, 1024);
}

// Round 5
// 243.515 us; speedup vs baseline: 1.1378x; 1.0517x over previous
//
#include <hip/hip_runtime.h>
#include <hip/hip_bf16.h>

typedef __bf16 bf16;
typedef __attribute__((ext_vector_type(8))) __bf16 bf16x8;
typedef __attribute__((ext_vector_type(4))) __bf16 bf16x4;
typedef __attribute__((ext_vector_type(2))) __bf16 bf16x2;
typedef __attribute__((ext_vector_type(4))) float f32x4;
typedef __attribute__((ext_vector_type(2))) unsigned int u32x2;
typedef __attribute__((ext_vector_type(4))) unsigned int u32x4;

#define MFMA16(a, b, c) __builtin_amdgcn_mfma_f32_16x16x32_bf16((a), (b), (c), 0, 0, 0)
#define SM_SCALE 0.18033688011112043f  // (1/8) * log2(e), folded into q at GEMM epilogue

__device__ __forceinline__ void gld_lds16(const bf16* g, bf16* l) {
    __builtin_amdgcn_global_load_lds((const __attribute__((address_space(1))) void*)g,
                                     (__attribute__((address_space(3))) void*)l, 16, 0, 0);
}

// raw barriers: no compiler-inserted vmcnt(0)/lgkmcnt(0) drain at each barrier.
#define PBAR() asm volatile("s_barrier" ::: "memory")
#define VWAIT0() asm volatile("s_waitcnt vmcnt(0)" ::: "memory")
#define VWAIT3() asm volatile("s_waitcnt vmcnt(3)" ::: "memory")

// ---------------- prep: W transpose (blocks 0..767) + x f32->bf16 (blocks 768..2815) --------
__global__ __launch_bounds__(256) void prep(const float* __restrict__ W0,
                                            const float* __restrict__ W1,
                                            const float* __restrict__ W2,
                                            bf16* __restrict__ Wt,
                                            const float* __restrict__ xin,
                                            bf16* __restrict__ xout) {
    __shared__ float tile[64][65];
    const int blk = blockIdx.x;
    const int tid = threadIdx.x;
    if (blk < 768) {
        const int z = blk >> 8, rem = blk & 255;
        const int r0 = (rem >> 4) * 64;  // k
        const int c0 = (rem & 15) * 64;  // n
        const float* W = (z == 0) ? W0 : ((z == 1) ? W1 : W2);
        bf16* dst = Wt + (size_t)z * 1024 * 1024;
        for (int i = tid; i < 4096; i += 256) {
            int r = i >> 6, cc = i & 63;
            tile[r][cc] = W[(size_t)(r0 + r) * 1024 + c0 + cc];
        }
        __syncthreads();
        for (int i = tid; i < 4096; i += 256) {
            int n = i >> 6, k = i & 63;
            dst[(size_t)(c0 + n) * 1024 + r0 + k] = (bf16)tile[k][n];
        }
    } else {
        // 2048 blocks x 256 threads x 16 floats = 8,388,608 = 8192*1024 exactly
        const size_t i0 = ((size_t)(blk - 768) * 256 + tid) * 16;
#pragma unroll
        for (int j = 0; j < 2; j++) {
            const float4 v0 = *(const float4*)(xin + i0 + j * 8);
            const float4 v1 = *(const float4*)(xin + i0 + j * 8 + 4);
            bf16x8 o = {(bf16)v0.x, (bf16)v0.y, (bf16)v0.z, (bf16)v0.w,
                        (bf16)v1.x, (bf16)v1.y, (bf16)v1.z, (bf16)v1.w};
            *(bf16x8*)(xout + i0 + j * 8) = o;
        }
    }
}

// ---------------- GEMM: 256x128 tile, BK=32, 8 waves (4Mx2N), 64x64/wave, 3-buf ----------------
// R11: prefetch-depth-2 pipeline. STAGE(kt+2) issues at kt top; STAGE(kt+1) drained at kt
// END via vmcnt(3) (kt+2's 3 loads stay in flight across the barrier -- never drain to 0
// mid-loop). Issue->wait distance = 2 tile bodies (~500+ cy) > HBM-miss latency.
// Buffer walk (race-free): buf[(kt+2)%3] == buf[(kt-1)%3], whose readers finished before
// kt-1's closing barrier; STAGE(kt)'s writes drained by kt-1's end-wait + published by
// kt-1's barrier before compute(kt) reads them. Tail: vmcnt(3)@kt<30, vmcnt(0)@kt==30.
// MODE 0: fused QKV (N=3072; q pre-scaled, v transposed into Vt). MODE 1: f32 out, N=1024.
template <int MODE>
__global__ __launch_bounds__(512, 4) void gemm_main(const bf16* __restrict__ A,
                                                    const bf16* __restrict__ Bt,
                                                    const float* __restrict__ b0,
                                                    const float* __restrict__ b1,
                                                    const float* __restrict__ b2,
                                                    void* __restrict__ out0,
                                                    void* __restrict__ out1,
                                                    void* __restrict__ out2,
                                                    int nbx) {
    __shared__ alignas(16) bf16 LDS[3 * 12288];  // per buf: A 256x32 @0 | B 128x32 @8192

    // XCD-chunked bijective swizzle (grid % 8 == 0): contiguous work chunk per XCD.
    const int orig = blockIdx.x;
    const int chunk = (int)gridDim.x >> 3;
    const int swz = (orig & 7) * chunk + (orig >> 3);
    const int by = swz / nbx, bx = swz % nbx;
    const int m0 = by * 256, n0 = bx * 128;

    const int tid = threadIdx.x;
    const int wid = tid >> 6, lane = tid & 63;
    const int wr = wid >> 1, wc = wid & 1;  // wave grid 4M x 2N; per-wave out 64x64
    const int quad = lane >> 4, l16 = lane & 15;

    // staging: thread t covers A rows (t>>2, 128+(t>>2)) and B row (t>>2), 16B chunk
    // (t&3); source col pre-swizzled so linear LDS + XOR read yields logical data.
    const int sr = tid >> 2;
    const int scol = (((tid & 3) ^ (sr & 3)) * 8);
    const bf16* gA = A + (size_t)(m0 + sr) * 1024 + scol;
    const bf16* gB = Bt + (size_t)(n0 + sr) * 1024 + scol;
    bf16* lA = &LDS[tid * 8];
    bf16* lB = &LDS[8192 + tid * 8];

    // read-side swizzled chunk (row&3 == l16&3 for all fragment rows)
    const int coff = ((quad ^ (l16 & 3)) * 8);

    f32x4 acc[4][4] = {};

    auto STAGE = [&](int kt, int p) {
        const int base = p * 12288;
        gld_lds16(gA + kt * 32, lA + base);
        gld_lds16(gA + kt * 32 + (size_t)128 * 1024, lA + base + 4096);
        gld_lds16(gB + kt * 32, lB + base);
    };

    STAGE(0, 0);
    STAGE(1, 1);
    VWAIT3();  // drain STAGE(0); STAGE(1) stays in flight
    PBAR();

    int rb = 0;   // read buffer for kt
    int sb = 2;   // stage buffer for kt+2
#pragma unroll 1
    for (int kt = 0; kt < 32; kt++) {
        const bf16* Asp = &LDS[rb * 12288];
        const bf16* Bsp = Asp + 8192;
        if (kt + 2 < 32) STAGE(kt + 2, sb);  // buf freed at kt-1's closing barrier

        bf16x8 af[4], bfr[4];
#pragma unroll
        for (int m4 = 0; m4 < 4; m4++)
            af[m4] = *(const bf16x8*)&Asp[(wr * 64 + m4 * 16 + l16) * 32 + coff];
#pragma unroll
        for (int ni = 0; ni < 4; ni++)
            bfr[ni] = *(const bf16x8*)&Bsp[(wc * 64 + ni * 16 + l16) * 32 + coff];

        __builtin_amdgcn_s_setprio(1);
#pragma unroll
        for (int m4 = 0; m4 < 4; m4++)
#pragma unroll
            for (int ni = 0; ni < 4; ni++)
                acc[m4][ni] = MFMA16(af[m4], bfr[ni], acc[m4][ni]);
        __builtin_amdgcn_s_setprio(0);

        if (kt < 30) {
            VWAIT3();  // drain STAGE(kt+1); STAGE(kt+2) flies across the barrier
            PBAR();    // publish kt+1; release buf[rb] for STAGE at kt+1's top
        } else if (kt == 30) {
            VWAIT0();  // last outstanding: STAGE(31)
            PBAR();
        }
        rb = (rb == 2) ? 0 : rb + 1;
        sb = (sb == 2) ? 0 : sb + 1;
    }

    // epilogue
    const int nl0 = (n0 & 1023) + wc * 64;
    const int mb0 = m0 + wr * 64;
    if (MODE == 0) {
        const int sel = n0 >> 10;  // 0=q, 1=k, 2=v  (128 | 1024 -> never straddles)
        if (sel < 2) {
            const float* bias = (sel == 0) ? b0 : b1;
            bf16* Cp = (bf16*)((sel == 0) ? out0 : out1);
            const float qs = (sel == 0) ? SM_SCALE : 1.0f;
#pragma unroll
            for (int mi = 0; mi < 4; mi++) {
                const int mbase = mb0 + mi * 16 + quad * 4;
#pragma unroll
                for (int ni = 0; ni < 4; ni++) {
                    const int nl = nl0 + ni * 16 + l16;
                    const float bv = bias[nl];
#pragma unroll
                    for (int r = 0; r < 4; r++)
                        Cp[(size_t)(mbase + r) * 1024 + nl] =
                            (bf16)((acc[mi][ni][r] + bv) * qs);
                }
            }
        } else {
            bf16* Vt = (bf16*)out2;
            const int b = m0 >> 11;  // 2048 rows/batch; 256-row block never straddles
#pragma unroll
            for (int ni = 0; ni < 4; ni++) {
                const int nl = nl0 + ni * 16 + l16;
                const int h = nl >> 6, d = nl & 63;
                const float bv = b2[nl];
                bf16* dst = Vt + ((size_t)(b * 16 + h) * 64 + d) * 2048;
#pragma unroll
                for (int mi = 0; mi < 4; mi++) {
                    const int t0 = (mb0 + mi * 16 + quad * 4) & 2047;  // batch-local t
                    bf16x4 w = {(bf16)(acc[mi][ni][0] + bv), (bf16)(acc[mi][ni][1] + bv),
                                (bf16)(acc[mi][ni][2] + bv), (bf16)(acc[mi][ni][3] + bv)};
                    *(bf16x4*)&dst[t0] = w;
                }
            }
        }
    } else {
        float* Cp = (float*)out0;
#pragma unroll
        for (int mi = 0; mi < 4; mi++) {
            const int mbase = mb0 + mi * 16 + quad * 4;
#pragma unroll
            for (int ni = 0; ni < 4; ni++) {
                const int n = n0 + wc * 64 + ni * 16 + l16;
                const float bv = b0[n];
#pragma unroll
                for (int r = 0; r < 4; r++)
                    Cp[(size_t)(mbase + r) * 1024 + n] = acc[mi][ni][r] + bv;
            }
        }
    }
}

// ---------------- flash attention, causal, hs=64 (R9 structure, unchanged) ----------------
template <bool NEEDMASK>
__device__ __forceinline__ void softmax_reg(const f32x4* st, bf16x8* pf, int qrel) {
    unsigned int p[4][2];
#pragma unroll
    for (int j = 0; j < 4; j++) {
        float pv[4];
#pragma unroll
        for (int r = 0; r < 4; r++) {
            float s = st[j][r];
            if (NEEDMASK && (j * 16 + r > qrel)) s = -1e30f;
            pv[r] = exp2f(s);
        }
        bf16x2 w0 = {(bf16)pv[0], (bf16)pv[1]};  // v_cvt_pk_bf16_f32 (compiler-fused)
        bf16x2 w1 = {(bf16)pv[2], (bf16)pv[3]};
        p[j][0] = __builtin_bit_cast(unsigned int, w0);
        p[j][1] = __builtin_bit_cast(unsigned int, w1);
    }
    // acc layout -> B-frag layout: permlane32_swap then permlane16_swap (l16 invariant)
#pragma unroll
    for (int ks = 0; ks < 2; ks++) {
        unsigned int q4[4];
#pragma unroll
        for (int h = 0; h < 2; h++) {
            u32x2 s32 = __builtin_amdgcn_permlane32_swap(p[2 * ks][h], p[2 * ks + 1][h],
                                                         false, false);
            u32x2 s16 = __builtin_amdgcn_permlane16_swap(s32[0], s32[1], false, false);
            q4[h] = s16[0];      // e2 = h     (kv ofs 2h, 2h+1)
            q4[2 + h] = s16[1];  // e2 = 2+h   (kv ofs 4+2h, 5+2h)
        }
        u32x4 qq = {q4[0], q4[1], q4[2], q4[3]};
        pf[ks] = __builtin_bit_cast(bf16x8, qq);
    }
}

__global__ __launch_bounds__(256, 4) void attn(const bf16* __restrict__ Q,
                                               const bf16* __restrict__ Kg,
                                               const bf16* __restrict__ Vt,
                                               bf16* __restrict__ O) {
    // bijective XCD swizzle: all 16 j-blocks of a (b,h) on one XCD (8 bh/XCD).
    const int lin = blockIdx.y * 16 + blockIdx.x;
    const int bh = (lin & 7) * 8 + ((lin >> 3) & 7);
    const int jb = lin >> 6;  // [0,16)
    const int b = bh >> 4, h = bh & 15;
    const int tid = threadIdx.x;
    const int wave = tid >> 6, lane = tid & 63;
    const int quad = lane >> 4, l16 = lane & 15;

    __shared__ alignas(16) bf16 KVs[2 * 8192];  // dbuf; per buf: K 64x64 | V^T 64x64 (swz)

    const bf16* Kbase = Kg + ((size_t)b * 2048) * 1024 + h * 64;
    const bf16* Vbase = Vt + (size_t)bh * 64 * 2048;

    const int srow = tid >> 3;
    const int schunk = (tid & 7) ^ (srow & 7);

    const int xorE = (l16 & 7) * 8;
    const int cofA = (quad * 8) ^ xorE;       // ks=0
    const int cofB = (32 + quad * 8) ^ xorE;  // ks=1

    const bf16 one1 = (bf16)1.0f;
    const bf16x8 onesf = {one1, one1, one1, one1, one1, one1, one1, one1};

#pragma unroll 1
    for (int phase = 0; phase < 2; phase++) {
        const int qs = (phase == 0) ? (31 - jb) : jb;
        const int q0 = qs * 64;
        const bf16* Qbase = Q + ((size_t)(b * 2048 + q0)) * 1024 + h * 64;

        bf16x8 qf[2];
#pragma unroll
        for (int ks = 0; ks < 2; ks++)
            qf[ks] = *(const bf16x8*)&Qbase[(size_t)(wave * 16 + l16) * 1024 + ks * 32 + quad * 8];

        f32x4 ot[4] = {};
        f32x4 lacc = {0.f, 0.f, 0.f, 0.f};
        const int ntiles = qs + 1;
        const int qrel = wave * 16 + l16 - quad * 4;

        const bf16* pK = Kbase + (size_t)srow * 1024 + schunk * 8;
        const bf16* pK2 = pK + (size_t)32 * 1024;
        const bf16* pV = Vbase + (size_t)srow * 2048 + schunk * 8;
        const bf16* pV2 = pV + (size_t)32 * 2048;

        {
            bf16* nb = &KVs[tid * 8];
            gld_lds16(pK, nb);
            gld_lds16(pK2, nb + 2048);
            gld_lds16(pV, nb + 4096);
            gld_lds16(pV2, nb + 6144);
            pK += 64 * 1024; pK2 += 64 * 1024; pV += 64; pV2 += 64;
        }
        VWAIT0();
        PBAR();

#pragma unroll 1
        for (int tk = 0; tk < ntiles; tk++) {
            const bf16* buf = &KVs[(tk & 1) * 8192];
            if (tk + 1 < ntiles) {
                bf16* nb = &KVs[((tk + 1) & 1) * 8192 + tid * 8];
                gld_lds16(pK, nb);
                gld_lds16(pK2, nb + 2048);
                gld_lds16(pV, nb + 4096);
                gld_lds16(pV2, nb + 6144);
                pK += 64 * 1024; pK2 += 64 * 1024; pV += 64; pV2 += 64;
            }

            f32x4 st[4] = {};
#pragma unroll
            for (int ks = 0; ks < 2; ks++)
#pragma unroll
                for (int j = 0; j < 4; j++) {
                    const bf16x8 kf =
                        *(const bf16x8*)&buf[(j * 16 + l16) * 64 + (ks ? cofB : cofA)];
                    st[j] = MFMA16(kf, qf[ks], st[j]);
                }

            bf16x8 pf[2];
            if (tk == ntiles - 1)
                softmax_reg<true>(st, pf, qrel);
            else
                softmax_reg<false>(st, pf, qrel);

            lacc = MFMA16(onesf, pf[0], lacc);
            lacc = MFMA16(onesf, pf[1], lacc);

#pragma unroll
            for (int ks = 0; ks < 2; ks++)
#pragma unroll
                for (int db = 0; db < 4; db++) {
                    const bf16x8 vf = *(const bf16x8*)&buf[4096 + (db * 16 + l16) * 64 +
                                                           (ks ? cofB : cofA)];
                    ot[db] = MFMA16(vf, pf[ks], ot[db]);
                }

            if (tk + 1 < ntiles) VWAIT0();
            PBAR();
        }

        const float inv = 1.f / lacc[0];
        bf16* ep = &KVs[(ntiles & 1) * 8192 + wave * (16 * 72)];
#pragma unroll
        for (int db = 0; db < 4; db++) {
            bf16x4 w = {(bf16)(ot[db][0] * inv), (bf16)(ot[db][1] * inv),
                        (bf16)(ot[db][2] * inv), (bf16)(ot[db][3] * inv)};
            *(bf16x4*)&ep[l16 * 72 + db * 16 + quad * 4] = w;
        }
        {
            const int orow = lane >> 2, oc = (lane & 3) * 16;
            bf16* Obase =
                O + ((size_t)(b * 2048 + q0 + wave * 16 + orow)) * 1024 + h * 64 + oc;
            const bf16* src = &ep[orow * 72 + oc];
            *(bf16x8*)&Obase[0] = *(const bf16x8*)&src[0];
            *(bf16x8*)&Obase[8] = *(const bf16x8*)&src[8];
        }
        __syncthreads();
    }
}

extern "C" void kernel_launch(void* const* d_in, const int* in_sizes, int n_in,
                              void* d_out, int out_size, void* d_ws, size_t ws_size,
                              hipStream_t stream) {
    const float* x = (const float*)d_in[0];
    const float* Wq = (const float*)d_in[1];
    const float* bq = (const float*)d_in[2];
    const float* Wk = (const float*)d_in[3];
    const float* bk = (const float*)d_in[4];
    const float* Wv = (const float*)d_in[5];
    const float* bv = (const float*)d_in[6];
    float* out = (float*)d_out;

    const int M = 8192;  // B*T
    const size_t sz_x = (size_t)M * 1024;
    const size_t sz_w = (size_t)1024 * 1024;

    char* p = (char*)d_ws;
    bf16* xb = (bf16*)p;   p += sz_x * 2;
    bf16* Wcat = (bf16*)p; p += 3 * sz_w * 2;  // [Wq^T ; Wk^T ; Wv^T]
    bf16* qb = (bf16*)p;   p += sz_x * 2;
    bf16* kb = (bf16*)p;   p += sz_x * 2;
    bf16* Vt = (bf16*)p;   p += sz_x * 2;  // [B*H][64][2048]
    bf16* yatt = (bf16*)p; p += sz_x * 2;

    // W transpose + x convert in one launch
    prep<<<dim3(2816), dim3(256), 0, stream>>>(Wq, Wk, Wv, Wcat, x, xb);

    // fused QKV projection: [8192,1024] @ [1024,3072] -- 256x128/BK32, 3-buf depth-2
    gemm_main<0><<<dim3(768), dim3(512), 0, stream>>>(xb, Wcat, bq, bk, bv, qb, kb, Vt, 24);
    attn<<<dim3(16, 64), dim3(256), 0, stream>>>(qb, kb, Vt, yatt);
    // output projection (reference reuses v_proj): yatt @ Wv + bv -> f32 out
    gemm_main<1><<<dim3(256), dim3(512), 0, stream>>>(yatt, Wcat + 2 * sz_w, bv, bv, bv,
                                                      out, out, out, 8);
}

// Round 6
// 229.138 us; speedup vs baseline: 1.2091x; 1.0627x over previous
//
#include <hip/hip_runtime.h>
#include <hip/hip_bf16.h>

typedef __bf16 bf16;
typedef __attribute__((ext_vector_type(8))) __bf16 bf16x8;
typedef __attribute__((ext_vector_type(4))) __bf16 bf16x4;
typedef __attribute__((ext_vector_type(2))) __bf16 bf16x2;
typedef __attribute__((ext_vector_type(4))) float f32x4;
typedef __attribute__((ext_vector_type(2))) unsigned int u32x2;
typedef __attribute__((ext_vector_type(4))) unsigned int u32x4;

#define MFMA16(a, b, c) __builtin_amdgcn_mfma_f32_16x16x32_bf16((a), (b), (c), 0, 0, 0)
#define SM_SCALE 0.18033688011112043f  // (1/8) * log2(e), folded into q at GEMM epilogue

__device__ __forceinline__ void gld_lds16(const bf16* g, bf16* l) {
    __builtin_amdgcn_global_load_lds((const __attribute__((address_space(1))) void*)g,
                                     (__attribute__((address_space(3))) void*)l, 16, 0, 0);
}

// raw barriers: no compiler-inserted vmcnt(0)/lgkmcnt(0) drain at each barrier.
#define PBAR() asm volatile("s_barrier" ::: "memory")
#define VWAIT0() asm volatile("s_waitcnt vmcnt(0)" ::: "memory")
#define VWAIT3() asm volatile("s_waitcnt vmcnt(3)" ::: "memory")
#define VWAIT4() asm volatile("s_waitcnt vmcnt(4)" ::: "memory")

// ---------------- prep: W transpose (blocks 0..767) + x f32->bf16 (blocks 768..2815) --------
__global__ __launch_bounds__(256) void prep(const float* __restrict__ W0,
                                            const float* __restrict__ W1,
                                            const float* __restrict__ W2,
                                            bf16* __restrict__ Wt,
                                            const float* __restrict__ xin,
                                            bf16* __restrict__ xout) {
    __shared__ float tile[64][65];
    const int blk = blockIdx.x;
    const int tid = threadIdx.x;
    if (blk < 768) {
        const int z = blk >> 8, rem = blk & 255;
        const int r0 = (rem >> 4) * 64;  // k
        const int c0 = (rem & 15) * 64;  // n
        const float* W = (z == 0) ? W0 : ((z == 1) ? W1 : W2);
        bf16* dst = Wt + (size_t)z * 1024 * 1024;
        for (int i = tid; i < 4096; i += 256) {
            int r = i >> 6, cc = i & 63;
            tile[r][cc] = W[(size_t)(r0 + r) * 1024 + c0 + cc];
        }
        __syncthreads();
        for (int i = tid; i < 4096; i += 256) {
            int n = i >> 6, k = i & 63;
            dst[(size_t)(c0 + n) * 1024 + r0 + k] = (bf16)tile[k][n];
        }
    } else {
        // 2048 blocks x 256 threads x 16 floats = 8,388,608 = 8192*1024 exactly
        const size_t i0 = ((size_t)(blk - 768) * 256 + tid) * 16;
#pragma unroll
        for (int j = 0; j < 2; j++) {
            const float4 v0 = *(const float4*)(xin + i0 + j * 8);
            const float4 v1 = *(const float4*)(xin + i0 + j * 8 + 4);
            bf16x8 o = {(bf16)v0.x, (bf16)v0.y, (bf16)v0.z, (bf16)v0.w,
                        (bf16)v1.x, (bf16)v1.y, (bf16)v1.z, (bf16)v1.w};
            *(bf16x8*)(xout + i0 + j * 8) = o;
        }
    }
}

// ---------------- GEMM: 256x128 tile, BK=32, 8 waves (4Mx2N), 64x64/wave, 3-buf ----------------
// (R11 structure, unchanged): prefetch-depth-2, counted vmcnt(3), never drain-to-0 mid-loop.
template <int MODE>
__global__ __launch_bounds__(512, 4) void gemm_main(const bf16* __restrict__ A,
                                                    const bf16* __restrict__ Bt,
                                                    const float* __restrict__ b0,
                                                    const float* __restrict__ b1,
                                                    const float* __restrict__ b2,
                                                    void* __restrict__ out0,
                                                    void* __restrict__ out1,
                                                    void* __restrict__ out2,
                                                    int nbx) {
    __shared__ alignas(16) bf16 LDS[3 * 12288];  // per buf: A 256x32 @0 | B 128x32 @8192

    // XCD-chunked bijective swizzle (grid % 8 == 0): contiguous work chunk per XCD.
    const int orig = blockIdx.x;
    const int chunk = (int)gridDim.x >> 3;
    const int swz = (orig & 7) * chunk + (orig >> 3);
    const int by = swz / nbx, bx = swz % nbx;
    const int m0 = by * 256, n0 = bx * 128;

    const int tid = threadIdx.x;
    const int wid = tid >> 6, lane = tid & 63;
    const int wr = wid >> 1, wc = wid & 1;  // wave grid 4M x 2N; per-wave out 64x64
    const int quad = lane >> 4, l16 = lane & 15;

    // staging: thread t covers A rows (t>>2, 128+(t>>2)) and B row (t>>2), 16B chunk
    // (t&3); source col pre-swizzled so linear LDS + XOR read yields logical data.
    const int sr = tid >> 2;
    const int scol = (((tid & 3) ^ (sr & 3)) * 8);
    const bf16* gA = A + (size_t)(m0 + sr) * 1024 + scol;
    const bf16* gB = Bt + (size_t)(n0 + sr) * 1024 + scol;
    bf16* lA = &LDS[tid * 8];
    bf16* lB = &LDS[8192 + tid * 8];

    // read-side swizzled chunk (row&3 == l16&3 for all fragment rows)
    const int coff = ((quad ^ (l16 & 3)) * 8);

    f32x4 acc[4][4] = {};

    auto STAGE = [&](int kt, int p) {
        const int base = p * 12288;
        gld_lds16(gA + kt * 32, lA + base);
        gld_lds16(gA + kt * 32 + (size_t)128 * 1024, lA + base + 4096);
        gld_lds16(gB + kt * 32, lB + base);
    };

    STAGE(0, 0);
    STAGE(1, 1);
    VWAIT3();  // drain STAGE(0); STAGE(1) stays in flight
    PBAR();

    int rb = 0;   // read buffer for kt
    int sb = 2;   // stage buffer for kt+2
#pragma unroll 1
    for (int kt = 0; kt < 32; kt++) {
        const bf16* Asp = &LDS[rb * 12288];
        const bf16* Bsp = Asp + 8192;
        if (kt + 2 < 32) STAGE(kt + 2, sb);  // buf freed at kt-1's closing barrier

        bf16x8 af[4], bfr[4];
#pragma unroll
        for (int m4 = 0; m4 < 4; m4++)
            af[m4] = *(const bf16x8*)&Asp[(wr * 64 + m4 * 16 + l16) * 32 + coff];
#pragma unroll
        for (int ni = 0; ni < 4; ni++)
            bfr[ni] = *(const bf16x8*)&Bsp[(wc * 64 + ni * 16 + l16) * 32 + coff];

        __builtin_amdgcn_s_setprio(1);
#pragma unroll
        for (int m4 = 0; m4 < 4; m4++)
#pragma unroll
            for (int ni = 0; ni < 4; ni++)
                acc[m4][ni] = MFMA16(af[m4], bfr[ni], acc[m4][ni]);
        __builtin_amdgcn_s_setprio(0);

        if (kt < 30) {
            VWAIT3();  // drain STAGE(kt+1); STAGE(kt+2) flies across the barrier
            PBAR();    // publish kt+1; release buf[rb] for STAGE at kt+1's top
        } else if (kt == 30) {
            VWAIT0();  // last outstanding: STAGE(31)
            PBAR();
        }
        rb = (rb == 2) ? 0 : rb + 1;
        sb = (sb == 2) ? 0 : sb + 1;
    }

    // epilogue
    const int nl0 = (n0 & 1023) + wc * 64;
    const int mb0 = m0 + wr * 64;
    if (MODE == 0) {
        const int sel = n0 >> 10;  // 0=q, 1=k, 2=v  (128 | 1024 -> never straddles)
        if (sel < 2) {
            const float* bias = (sel == 0) ? b0 : b1;
            bf16* Cp = (bf16*)((sel == 0) ? out0 : out1);
            const float qs = (sel == 0) ? SM_SCALE : 1.0f;
#pragma unroll
            for (int mi = 0; mi < 4; mi++) {
                const int mbase = mb0 + mi * 16 + quad * 4;
#pragma unroll
                for (int ni = 0; ni < 4; ni++) {
                    const int nl = nl0 + ni * 16 + l16;
                    const float bv = bias[nl];
#pragma unroll
                    for (int r = 0; r < 4; r++)
                        Cp[(size_t)(mbase + r) * 1024 + nl] =
                            (bf16)((acc[mi][ni][r] + bv) * qs);
                }
            }
        } else {
            bf16* Vt = (bf16*)out2;
            const int b = m0 >> 11;  // 2048 rows/batch; 256-row block never straddles
#pragma unroll
            for (int ni = 0; ni < 4; ni++) {
                const int nl = nl0 + ni * 16 + l16;
                const int h = nl >> 6, d = nl & 63;
                const float bv = b2[nl];
                bf16* dst = Vt + ((size_t)(b * 16 + h) * 64 + d) * 2048;
#pragma unroll
                for (int mi = 0; mi < 4; mi++) {
                    const int t0 = (mb0 + mi * 16 + quad * 4) & 2047;  // batch-local t
                    bf16x4 w = {(bf16)(acc[mi][ni][0] + bv), (bf16)(acc[mi][ni][1] + bv),
                                (bf16)(acc[mi][ni][2] + bv), (bf16)(acc[mi][ni][3] + bv)};
                    *(bf16x4*)&dst[t0] = w;
                }
            }
        }
    } else {
        float* Cp = (float*)out0;
#pragma unroll
        for (int mi = 0; mi < 4; mi++) {
            const int mbase = mb0 + mi * 16 + quad * 4;
#pragma unroll
            for (int ni = 0; ni < 4; ni++) {
                const int n = n0 + wc * 64 + ni * 16 + l16;
                const float bv = b0[n];
#pragma unroll
                for (int r = 0; r < 4; r++)
                    Cp[(size_t)(mbase + r) * 1024 + n] = acc[mi][ni][r] + bv;
            }
        }
    }
}

// ---------------- flash attention, causal, hs=64 ----------------
// R12 vs R9: 3-LDS-buffer rotation, prefetch depth 2, counted vmcnt(4) (never 0 mid-loop)
// -- the same T4 mechanism that fixed the QKV GEMM. stage(t+2) issues at t's top; its
// drain is at t+1's END (distance = 2 tile bodies > L3 latency). Buffer walk race-free:
// buf[(t+2)%3]'s readers (tile t-1) finished before t-1's closing barrier; vmcnt(4) at
// t's end leaves exactly stage(t+2)'s 4 loads in flight across the barrier; tail uses
// vmcnt(0) when t+2>=ntiles. Prologue stages tiles 0,1 unguarded (always in-bounds;
// unused if ntiles==1; phase-end __syncthreads drains the stray). Epilogue scratch uses
// buf[(ntiles+1)%3] (never a pending-write target for any ntiles). exp2f -> builtin.
template <bool NEEDMASK>
__device__ __forceinline__ void softmax_reg(const f32x4* st, bf16x8* pf, int qrel) {
    unsigned int p[4][2];
#pragma unroll
    for (int j = 0; j < 4; j++) {
        float pv[4];
#pragma unroll
        for (int r = 0; r < 4; r++) {
            float s = st[j][r];
            if (NEEDMASK && (j * 16 + r > qrel)) s = -1e30f;
            pv[r] = __builtin_amdgcn_exp2f(s);
        }
        bf16x2 w0 = {(bf16)pv[0], (bf16)pv[1]};  // v_cvt_pk_bf16_f32 (compiler-fused)
        bf16x2 w1 = {(bf16)pv[2], (bf16)pv[3]};
        p[j][0] = __builtin_bit_cast(unsigned int, w0);
        p[j][1] = __builtin_bit_cast(unsigned int, w1);
    }
    // acc layout -> B-frag layout: permlane32_swap then permlane16_swap (l16 invariant)
#pragma unroll
    for (int ks = 0; ks < 2; ks++) {
        unsigned int q4[4];
#pragma unroll
        for (int h = 0; h < 2; h++) {
            u32x2 s32 = __builtin_amdgcn_permlane32_swap(p[2 * ks][h], p[2 * ks + 1][h],
                                                         false, false);
            u32x2 s16 = __builtin_amdgcn_permlane16_swap(s32[0], s32[1], false, false);
            q4[h] = s16[0];      // e2 = h     (kv ofs 2h, 2h+1)
            q4[2 + h] = s16[1];  // e2 = 2+h   (kv ofs 4+2h, 5+2h)
        }
        u32x4 qq = {q4[0], q4[1], q4[2], q4[3]};
        pf[ks] = __builtin_bit_cast(bf16x8, qq);
    }
}

__global__ __launch_bounds__(256, 3) void attn(const bf16* __restrict__ Q,
                                               const bf16* __restrict__ Kg,
                                               const bf16* __restrict__ Vt,
                                               bf16* __restrict__ O) {
    // bijective XCD swizzle: all 16 j-blocks of a (b,h) on one XCD (8 bh/XCD).
    const int lin = blockIdx.y * 16 + blockIdx.x;
    const int bh = (lin & 7) * 8 + ((lin >> 3) & 7);
    const int jb = lin >> 6;  // [0,16)
    const int b = bh >> 4, h = bh & 15;
    const int tid = threadIdx.x;
    const int wave = tid >> 6, lane = tid & 63;
    const int quad = lane >> 4, l16 = lane & 15;

    __shared__ alignas(16) bf16 KVs[3 * 8192];  // 3-buf; per buf: K 64x64 | V^T 64x64 (swz)

    const bf16* Kbase = Kg + ((size_t)b * 2048) * 1024 + h * 64;
    const bf16* Vbase = Vt + (size_t)bh * 64 * 2048;

    const int srow = tid >> 3;
    const int schunk = (tid & 7) ^ (srow & 7);

    const int xorE = (l16 & 7) * 8;
    const int cofA = (quad * 8) ^ xorE;       // ks=0
    const int cofB = (32 + quad * 8) ^ xorE;  // ks=1

    const bf16 one1 = (bf16)1.0f;
    const bf16x8 onesf = {one1, one1, one1, one1, one1, one1, one1, one1};

#pragma unroll 1
    for (int phase = 0; phase < 2; phase++) {
        const int qs = (phase == 0) ? (31 - jb) : jb;
        const int q0 = qs * 64;
        const bf16* Qbase = Q + ((size_t)(b * 2048 + q0)) * 1024 + h * 64;

        bf16x8 qf[2];
#pragma unroll
        for (int ks = 0; ks < 2; ks++)
            qf[ks] = *(const bf16x8*)&Qbase[(size_t)(wave * 16 + l16) * 1024 + ks * 32 + quad * 8];

        f32x4 ot[4] = {};
        f32x4 lacc = {0.f, 0.f, 0.f, 0.f};
        const int ntiles = qs + 1;
        const int qrel = wave * 16 + l16 - quad * 4;

        const bf16* pK = Kbase + (size_t)srow * 1024 + schunk * 8;
        const bf16* pK2 = pK + (size_t)32 * 1024;
        const bf16* pV = Vbase + (size_t)srow * 2048 + schunk * 8;
        const bf16* pV2 = pV + (size_t)32 * 2048;

        // prologue: stage tiles 0 and 1 (tile 1 rows always in-bounds; unused if ntiles==1)
        {
            bf16* nb = &KVs[tid * 8];
            gld_lds16(pK, nb);
            gld_lds16(pK2, nb + 2048);
            gld_lds16(pV, nb + 4096);
            gld_lds16(pV2, nb + 6144);
            pK += 64 * 1024; pK2 += 64 * 1024; pV += 64; pV2 += 64;
            nb = &KVs[8192 + tid * 8];
            gld_lds16(pK, nb);
            gld_lds16(pK2, nb + 2048);
            gld_lds16(pV, nb + 4096);
            gld_lds16(pV2, nb + 6144);
            pK += 64 * 1024; pK2 += 64 * 1024; pV += 64; pV2 += 64;
        }
        VWAIT4();  // drain stage(0); stage(1) stays in flight
        PBAR();

        int rbuf = 0, sbuf = 2;
#pragma unroll 1
        for (int tk = 0; tk < ntiles; tk++) {
            const bf16* buf = &KVs[rbuf * 8192];
            if (tk + 2 < ntiles) {  // stage(t+2): drained at t+1's end (2 bodies away)
                bf16* nb = &KVs[sbuf * 8192 + tid * 8];
                gld_lds16(pK, nb);
                gld_lds16(pK2, nb + 2048);
                gld_lds16(pV, nb + 4096);
                gld_lds16(pV2, nb + 6144);
                pK += 64 * 1024; pK2 += 64 * 1024; pV += 64; pV2 += 64;
            }

            // S^T = K . Q^T
            f32x4 st[4] = {};
#pragma unroll
            for (int ks = 0; ks < 2; ks++)
#pragma unroll
                for (int j = 0; j < 4; j++) {
                    const bf16x8 kf =
                        *(const bf16x8*)&buf[(j * 16 + l16) * 64 + (ks ? cofB : cofA)];
                    st[j] = MFMA16(kf, qf[ks], st[j]);
                }

            // softmax + in-register P redistribution
            bf16x8 pf[2];
            if (tk == ntiles - 1)
                softmax_reg<true>(st, pf, qrel);
            else
                softmax_reg<false>(st, pf, qrel);

            // l-sum via MFMA ones-fragment
            lacc = MFMA16(onesf, pf[0], lacc);
            lacc = MFMA16(onesf, pf[1], lacc);

            // O^T += V^T . P^T
#pragma unroll
            for (int ks = 0; ks < 2; ks++)
#pragma unroll
                for (int db = 0; db < 4; db++) {
                    const bf16x8 vf = *(const bf16x8*)&buf[4096 + (db * 16 + l16) * 64 +
                                                           (ks ? cofB : cofA)];
                    ot[db] = MFMA16(vf, pf[ks], ot[db]);
                }

            if (tk + 1 < ntiles) {
                if (tk + 2 < ntiles) VWAIT4();  // drain stage(t+1); stage(t+2) in flight
                else VWAIT0();                  // tail: drain the last stage
                PBAR();                         // publish t+1; buf[rbuf] readers done
            }
            rbuf = (rbuf == 2) ? 0 : rbuf + 1;
            sbuf = (sbuf == 2) ? 0 : sbuf + 1;
        }

        // epilogue: O^T regs -> transpose staging in buf[(ntiles+1)%3] (idle: its last
        // readers finished at tile ntiles-2's barrier; never a pending gld_lds target).
        const float inv = 1.f / lacc[0];
        bf16* ep = &KVs[((ntiles + 1) % 3) * 8192 + wave * (16 * 72)];
#pragma unroll
        for (int db = 0; db < 4; db++) {
            bf16x4 w = {(bf16)(ot[db][0] * inv), (bf16)(ot[db][1] * inv),
                        (bf16)(ot[db][2] * inv), (bf16)(ot[db][3] * inv)};
            *(bf16x4*)&ep[l16 * 72 + db * 16 + quad * 4] = w;
        }
        {
            const int orow = lane >> 2, oc = (lane & 3) * 16;
            bf16* Obase =
                O + ((size_t)(b * 2048 + q0 + wave * 16 + orow)) * 1024 + h * 64 + oc;
            const bf16* src = &ep[orow * 72 + oc];
            *(bf16x8*)&Obase[0] = *(const bf16x8*)&src[0];
            *(bf16x8*)&Obase[8] = *(const bf16x8*)&src[8];
        }
        __syncthreads();  // full drain (incl. stray ntiles==1 stage) + epilogue reads done
    }
}

extern "C" void kernel_launch(void* const* d_in, const int* in_sizes, int n_in,
                              void* d_out, int out_size, void* d_ws, size_t ws_size,
                              hipStream_t stream) {
    const float* x = (const float*)d_in[0];
    const float* Wq = (const float*)d_in[1];
    const float* bq = (const float*)d_in[2];
    const float* Wk = (const float*)d_in[3];
    const float* bk = (const float*)d_in[4];
    const float* Wv = (const float*)d_in[5];
    const float* bv = (const float*)d_in[6];
    float* out = (float*)d_out;

    const int M = 8192;  // B*T
    const size_t sz_x = (size_t)M * 1024;
    const size_t sz_w = (size_t)1024 * 1024;

    char* p = (char*)d_ws;
    bf16* xb = (bf16*)p;   p += sz_x * 2;
    bf16* Wcat = (bf16*)p; p += 3 * sz_w * 2;  // [Wq^T ; Wk^T ; Wv^T]
    bf16* qb = (bf16*)p;   p += sz_x * 2;
    bf16* kb = (bf16*)p;   p += sz_x * 2;
    bf16* Vt = (bf16*)p;   p += sz_x * 2;  // [B*H][64][2048]
    bf16* yatt = (bf16*)p; p += sz_x * 2;

    // W transpose + x convert in one launch
    prep<<<dim3(2816), dim3(256), 0, stream>>>(Wq, Wk, Wv, Wcat, x, xb);

    // fused QKV projection: [8192,1024] @ [1024,3072] -- 256x128/BK32, 3-buf depth-2
    gemm_main<0><<<dim3(768), dim3(512), 0, stream>>>(xb, Wcat, bq, bk, bv, qb, kb, Vt, 24);
    attn<<<dim3(16, 64), dim3(256), 0, stream>>>(qb, kb, Vt, yatt);
    // output projection (reference reuses v_proj): yatt @ Wv + bv -> f32 out
    gemm_main<1><<<dim3(256), dim3(512), 0, stream>>>(yatt, Wcat + 2 * sz_w, bv, bv, bv,
                                                      out, out, out, 8);
}